// Round 1
// baseline (1377.260 us; speedup 1.0000x reference)
//
#include <hip/hip_runtime.h>
#include <math.h>

#define NE 8
#define NT 512
#define NH 1024
#define NF 2816
#define NG 128
#define TWO_F (2*NF)      // 5632
#define HP (NH/8)         // 128 packed rows for w13
#define FP (NF/8)         // 352 packed rows for w2
#define H_GROUPS (NH/NG)  // 8
#define F_GROUPS (NF/NG)  // 22

// ---------------- routing: softmax -> top2 -> renormalize ----------------
__global__ void route_kernel(const float* __restrict__ logits,
                             int* __restrict__ topk_i,
                             float* __restrict__ topk_w) {
    int t = blockIdx.x * blockDim.x + threadIdx.x;
    if (t >= NT) return;
    float l[NE];
#pragma unroll
    for (int e = 0; e < NE; ++e) l[e] = logits[t * NE + e];
    // top-1 (earliest index on ties, matching jax.lax.top_k)
    int i0 = 0; float v0 = l[0];
#pragma unroll
    for (int e = 1; e < NE; ++e) { if (l[e] > v0) { v0 = l[e]; i0 = e; } }
    // top-2
    int i1 = -1; float v1 = -INFINITY;
#pragma unroll
    for (int e = 0; e < NE; ++e) {
        if (e == i0) continue;
        if (l[e] > v1) { v1 = l[e]; i1 = e; }
    }
    // normalized top-2 softmax weights: exp cancels the full-Z
    float e1 = expf(v1 - v0);
    float inv = 1.0f / (1.0f + e1);
    topk_i[t * 2 + 0] = i0;
    topk_i[t * 2 + 1] = i1;
    topk_w[t * 2 + 0] = inv;
    topk_w[t * 2 + 1] = e1 * inv;
}

// ---------------- main fused MoE: one block per token ----------------
__global__ __launch_bounds__(256) void moe_kernel(
        const float* __restrict__ x,
        const int*   __restrict__ w13q,
        const int*   __restrict__ w2q,
        const float* __restrict__ s13,
        const float* __restrict__ s2,
        const int*   __restrict__ topk_i,
        const float* __restrict__ topk_w,
        float* __restrict__ out) {
    __shared__ float xs[NH];        // x row
    __shared__ float xs8n[HP];      // -8 * sum of each 8-pack of x
    __shared__ float as[NF];        // silu(g)*u activations
    __shared__ float as8n[FP];      // -8 * sum of each 8-pack of a

    const int tid = threadIdx.x;
    const int t   = blockIdx.x;

    // stage x row
#pragma unroll
    for (int j = 0; j < NH / 256; ++j)
        xs[j * 256 + tid] = x[t * NH + j * 256 + tid];
    __syncthreads();
    if (tid < HP) {
        float s = 0.f;
#pragma unroll
        for (int p = 0; p < 8; ++p) s += xs[tid * 8 + p];
        xs8n[tid] = -8.f * s;
    }
    __syncthreads();

    float acc[NH / 256];
#pragma unroll
    for (int j = 0; j < NH / 256; ++j) acc[j] = 0.f;

    for (int slot = 0; slot < 2; ++slot) {
        const int   e   = topk_i[t * 2 + slot];
        const float wgt = topk_w[t * 2 + slot];

        const int*   wq = w13q + (size_t)e * HP * TWO_F;
        const float* sc = s13  + (size_t)e * H_GROUPS * TWO_F;

        // ---- phase A: h = x @ W13 ; a = silu(g)*u  (f and f+NF together) ----
        for (int f = tid; f < NF; f += 256) {
            float gacc = 0.f, uacc = 0.f;
            for (int grp = 0; grp < H_GROUPS; ++grp) {
                float gg = 0.f, uu = 0.f;
#pragma unroll
                for (int kp = grp * 16; kp < grp * 16 + 16; ++kp) {
                    const int qg = wq[kp * TWO_F + f];
                    const int qu = wq[kp * TWO_F + f + NF];
#pragma unroll
                    for (int p = 0; p < 8; ++p) {
                        const float xv = xs[kp * 8 + p];
                        gg += (float)((qg >> (4 * p)) & 15) * xv;
                        uu += (float)((qu >> (4 * p)) & 15) * xv;
                    }
                    const float c8 = xs8n[kp];
                    gg += c8;
                    uu += c8;
                }
                gacc += gg * sc[grp * TWO_F + f];
                uacc += uu * sc[grp * TWO_F + f + NF];
            }
            const float silu = gacc / (1.f + __expf(-gacc));
            as[f] = silu * uacc;
        }
        __syncthreads();
        for (int fp = tid; fp < FP; fp += 256) {
            float s = 0.f;
#pragma unroll
            for (int p = 0; p < 8; ++p) s += as[fp * 8 + p];
            as8n[fp] = -8.f * s;
        }
        __syncthreads();

        // ---- phase B: y = a @ W2, weighted accumulate ----
        const int*   wq2 = w2q + (size_t)e * FP * NH;
        const float* sc2 = s2  + (size_t)e * F_GROUPS * NH;
#pragma unroll
        for (int j = 0; j < NH / 256; ++j) {
            const int hh = j * 256 + tid;
            float ysum = 0.f;
            for (int grp = 0; grp < F_GROUPS; ++grp) {
                float gg = 0.f;
#pragma unroll
                for (int fp = grp * 16; fp < grp * 16 + 16; ++fp) {
                    const int q = wq2[fp * NH + hh];
#pragma unroll
                    for (int p = 0; p < 8; ++p)
                        gg += (float)((q >> (4 * p)) & 15) * as[fp * 8 + p];
                    gg += as8n[fp];
                }
                ysum += gg * sc2[grp * NH + hh];
            }
            acc[j] += wgt * ysum;
        }
        __syncthreads();   // protect `as` before next slot overwrites
    }

#pragma unroll
    for (int j = 0; j < NH / 256; ++j)
        out[t * NH + j * 256 + tid] = acc[j];
}

extern "C" void kernel_launch(void* const* d_in, const int* in_sizes, int n_in,
                              void* d_out, int out_size, void* d_ws, size_t ws_size,
                              hipStream_t stream) {
    const float* x      = (const float*)d_in[0];
    const float* logits = (const float*)d_in[1];
    const int*   w13q   = (const int*)d_in[2];
    const int*   w2q    = (const int*)d_in[3];
    const float* s13    = (const float*)d_in[4];
    const float* s2     = (const float*)d_in[5];
    // d_in[6] = top_k, fixed at 2 for this problem shape

    int*   topk_i = (int*)d_ws;
    float* topk_w = (float*)((char*)d_ws + NT * 2 * sizeof(int));

    route_kernel<<<2, 256, 0, stream>>>(logits, topk_i, topk_w);
    moe_kernel<<<NT, 256, 0, stream>>>(x, w13q, w2q, s13, s2,
                                       topk_i, topk_w, (float*)d_out);
}

// Round 2
// 161.227 us; speedup vs baseline: 8.5424x; 8.5424x over previous
//
#include <hip/hip_runtime.h>
#include <math.h>

#define NE 8
#define NT 512
#define NH 1024
#define NF 2816
#define NG 128
#define TWO_F (2*NF)      // 5632
#define HP (NH/8)         // 128 packed rows for w13
#define FP (NF/8)         // 352 packed rows for w2
#define H_GROUPS (NH/NG)  // 8
#define F_GROUPS (NF/NG)  // 22

typedef __attribute__((ext_vector_type(8))) short short8;
typedef __attribute__((ext_vector_type(4))) float f32x4;

__device__ inline short f2bf(float f) {
    unsigned u = __float_as_uint(f);
    u += 0x7FFFu + ((u >> 16) & 1u);   // RNE
    return (short)(u >> 16);
}
__device__ inline float bf2f(short s) {
    return __uint_as_float(((unsigned)(unsigned short)s) << 16);
}

// unpack 8 int4 nibbles -> (nib-8)*sc as bf16 (truncation pack via v_perm)
__device__ inline short8 unpack_scale(int q, float sc) {
    float v[8];
#pragma unroll
    for (int j = 0; j < 8; ++j) {
        unsigned u = 0x4B000000u | (((unsigned)q >> (4 * j)) & 15u);
        v[j] = __uint_as_float(u) - 8388616.0f;   // exact (nib - 8)
    }
    union { short8 s; unsigned u[4]; } r;
#pragma unroll
    for (int j = 0; j < 4; ++j) {
        unsigned lo = __float_as_uint(v[2 * j] * sc);
        unsigned hi = __float_as_uint(v[2 * j + 1] * sc);
        r.u[j] = __builtin_amdgcn_perm(hi, lo, 0x07060302u);  // [bf16(lo), bf16(hi)]
    }
    return r.s;
}

// ---------------- routing: softmax -> top2 -> renormalize ----------------
__global__ void route_kernel(const float* __restrict__ logits,
                             int* __restrict__ topk_i,
                             float* __restrict__ topk_w) {
    int t = blockIdx.x * blockDim.x + threadIdx.x;
    if (t >= NT) return;
    float l[NE];
#pragma unroll
    for (int e = 0; e < NE; ++e) l[e] = logits[t * NE + e];
    int i0 = 0; float v0 = l[0];
#pragma unroll
    for (int e = 1; e < NE; ++e) { if (l[e] > v0) { v0 = l[e]; i0 = e; } }
    int i1 = -1; float v1 = -INFINITY;
#pragma unroll
    for (int e = 0; e < NE; ++e) {
        if (e == i0) continue;
        if (l[e] > v1) { v1 = l[e]; i1 = e; }
    }
    float e1 = expf(v1 - v0);
    float inv = 1.0f / (1.0f + e1);
    topk_i[t * 2 + 0] = i0;
    topk_i[t * 2 + 1] = i1;
    topk_w[t * 2 + 0] = inv;
    topk_w[t * 2 + 1] = e1 * inv;
}

// ---------------- x -> bf16 ----------------
__global__ void cvt_x_kernel(const float* __restrict__ x, short* __restrict__ x_bf) {
    int idx = (blockIdx.x * 256 + threadIdx.x) * 8;
    f32x4 f0 = *(const f32x4*)(x + idx);
    f32x4 f1 = *(const f32x4*)(x + idx + 4);
    short8 o;
#pragma unroll
    for (int j = 0; j < 4; ++j) o[j] = f2bf(f0[j]);
#pragma unroll
    for (int j = 0; j < 4; ++j) o[4 + j] = f2bf(f1[j]);
    *(short8*)(x_bf + idx) = o;
}

// ---------------- stable expert binning (8 waves, wave w = expert w) ------
__global__ __launch_bounds__(512) void bin_kernel(const int* __restrict__ topk_i,
                                                  int* __restrict__ counts,
                                                  int* __restrict__ tok_list) {
    __shared__ int sh_e[2 * NT];
    int tid = threadIdx.x;
    sh_e[tid] = topk_i[tid];
    sh_e[tid + 512] = topk_i[tid + 512];
    __syncthreads();
    int w = tid >> 6;      // expert
    int l = tid & 63;
    int base = 0;
    for (int chunk = 0; chunk < 16; ++chunk) {
        int j = chunk * 64 + l;
        bool m = (sh_e[j] == w);
        unsigned long long mask = __ballot(m);
        if (m) {
            int pos = base + __popcll(mask & ((1ull << l) - 1ull));
            tok_list[w * NT + pos] = j;   // j = t*2 + slot
        }
        base += __popcll(mask);
    }
    if (l == 0) counts[w] = base;
}

// ---------------- GEMM1: h = X_e @ W13_e  (tile 128x128, 4 waves 2x2) ------
__global__ __launch_bounds__(256) void gemm1_kernel(
        const short* __restrict__ x_bf,
        const int*   __restrict__ w13q,
        const float* __restrict__ s13,
        const int*   __restrict__ counts,
        const int*   __restrict__ tok_list,
        short* __restrict__ h_ws) {
    const int e = blockIdx.z;
    const int me = counts[e];
    const int mtile = blockIdx.y;
    if (mtile * 128 >= me) return;
    const int ntile = blockIdx.x;
    const int tid = threadIdx.x;
    const int w = tid >> 6, l = tid & 63;
    const int lr = l & 15, kg = l >> 4;
    const int mh = w >> 1, nh = w & 1;
    const int rb = mtile * 128 + mh * 64;
    const int cb = ntile * 128 + nh * 64;
    const int* tl = tok_list + e * NT;

    const short* xA[4];
#pragma unroll
    for (int ms = 0; ms < 4; ++ms) {
        int i = rb + ms * 16 + lr;
        if (i >= me) i = me - 1;
        xA[ms] = x_bf + (size_t)(tl[i] >> 1) * NH;
    }

    f32x4 acc[4][4];
#pragma unroll
    for (int ms = 0; ms < 4; ++ms)
#pragma unroll
        for (int ns = 0; ns < 4; ++ns) acc[ms][ns] = (f32x4)0.0f;

    for (int kb = 0; kb < H_GROUPS; ++kb) {
        float sc[4];
#pragma unroll
        for (int ns = 0; ns < 4; ++ns)
            sc[ns] = s13[(size_t)(e * H_GROUPS + kb) * TWO_F + cb + ns * 16 + lr];
#pragma unroll
        for (int ks = 0; ks < 4; ++ks) {
            const int k0 = kb * 128 + ks * 32;
            short8 a[4];
#pragma unroll
            for (int ms = 0; ms < 4; ++ms)
                a[ms] = *(const short8*)(xA[ms] + k0 + kg * 8);
            const int kp = (k0 >> 3) + kg;
            const int* bq = w13q + ((size_t)e * HP + kp) * TWO_F + cb + lr;
#pragma unroll
            for (int ns = 0; ns < 4; ++ns) {
                int q = bq[ns * 16];
                short8 b = unpack_scale(q, sc[ns]);
#pragma unroll
                for (int ms = 0; ms < 4; ++ms)
                    acc[ms][ns] = __builtin_amdgcn_mfma_f32_16x16x32_bf16(
                        a[ms], b, acc[ms][ns], 0, 0, 0);
            }
        }
    }
    // epilogue: C row = (lane>>4)*4 + reg, col = lane&15
#pragma unroll
    for (int ms = 0; ms < 4; ++ms) {
        const int rbase = rb + ms * 16 + kg * 4;
#pragma unroll
        for (int r = 0; r < 4; ++r) {
            const int orow = rbase + r;
            if (orow < me) {
                const int t2s = tl[orow];
                short* dst = h_ws + (size_t)t2s * TWO_F + cb + lr;
#pragma unroll
                for (int ns = 0; ns < 4; ++ns)
                    dst[ns * 16] = f2bf(acc[ms][ns][r]);
            }
        }
    }
}

// ---------------- activation: a = silu(g)*u ----------------
__global__ __launch_bounds__(384) void act_kernel(const short* __restrict__ h_ws,
                                                  short* __restrict__ a_ws) {
    const int row = blockIdx.x;
    const int f8 = threadIdx.x;
    if (f8 >= NF / 8) return;
    const short8 g8 = *(const short8*)(h_ws + (size_t)row * TWO_F + f8 * 8);
    const short8 u8 = *(const short8*)(h_ws + (size_t)row * TWO_F + NF + f8 * 8);
    short8 o;
#pragma unroll
    for (int j = 0; j < 8; ++j) {
        float g = bf2f(g8[j]);
        float u = bf2f(u8[j]);
        float s = g / (1.0f + __expf(-g));
        o[j] = f2bf(s * u);
    }
    *(short8*)(a_ws + (size_t)row * NF + f8 * 8) = o;
}

// ---------------- GEMM2: y = A_e @ W2_e (tile 64x128, wave n-strips) -------
__global__ __launch_bounds__(256) void gemm2_kernel(
        const short* __restrict__ a_ws,
        const int*   __restrict__ w2q,
        const float* __restrict__ s2,
        const int*   __restrict__ counts,
        const int*   __restrict__ tok_list,
        float* __restrict__ y_ws) {
    const int e = blockIdx.z;
    const int me = counts[e];
    const int mtile = blockIdx.y;
    if (mtile * 64 >= me) return;
    const int ntile = blockIdx.x;
    const int tid = threadIdx.x;
    const int w = tid >> 6, l = tid & 63;
    const int lr = l & 15, kg = l >> 4;
    const int rb = mtile * 64;
    const int cb = ntile * 128 + w * 32;
    const int* tl = tok_list + e * NT;

    const short* aA[4];
#pragma unroll
    for (int ms = 0; ms < 4; ++ms) {
        int i = rb + ms * 16 + lr;
        if (i >= me) i = me - 1;
        aA[ms] = a_ws + (size_t)tl[i] * NF;
    }

    f32x4 acc[4][2];
#pragma unroll
    for (int ms = 0; ms < 4; ++ms)
#pragma unroll
        for (int ns = 0; ns < 2; ++ns) acc[ms][ns] = (f32x4)0.0f;

    for (int kb = 0; kb < F_GROUPS; ++kb) {
        float sc[2];
#pragma unroll
        for (int ns = 0; ns < 2; ++ns)
            sc[ns] = s2[(size_t)(e * F_GROUPS + kb) * NH + cb + ns * 16 + lr];
#pragma unroll
        for (int ks = 0; ks < 4; ++ks) {
            const int k0 = kb * 128 + ks * 32;
            short8 a[4];
#pragma unroll
            for (int ms = 0; ms < 4; ++ms)
                a[ms] = *(const short8*)(aA[ms] + k0 + kg * 8);
            const int kp = (k0 >> 3) + kg;
            const int* bq = w2q + ((size_t)e * FP + kp) * NH + cb + lr;
#pragma unroll
            for (int ns = 0; ns < 2; ++ns) {
                int q = bq[ns * 16];
                short8 b = unpack_scale(q, sc[ns]);
#pragma unroll
                for (int ms = 0; ms < 4; ++ms)
                    acc[ms][ns] = __builtin_amdgcn_mfma_f32_16x16x32_bf16(
                        a[ms], b, acc[ms][ns], 0, 0, 0);
            }
        }
    }
#pragma unroll
    for (int ms = 0; ms < 4; ++ms) {
        const int rbase = rb + ms * 16 + kg * 4;
#pragma unroll
        for (int r = 0; r < 4; ++r) {
            const int orow = rbase + r;
            if (orow < me) {
                const int t2s = tl[orow];
                float* dst = y_ws + (size_t)t2s * NH + cb + lr;
#pragma unroll
                for (int ns = 0; ns < 2; ++ns)
                    dst[ns * 16] = acc[ms][ns][r];
            }
        }
    }
}

// ---------------- combine: out = w0*y0 + w1*y1 ----------------
__global__ __launch_bounds__(256) void combine_kernel(const float* __restrict__ y_ws,
                                                      const float* __restrict__ topk_w,
                                                      float* __restrict__ out) {
    const int t = blockIdx.x;
    const int c = threadIdx.x * 4;
    const float w0 = topk_w[t * 2 + 0];
    const float w1 = topk_w[t * 2 + 1];
    f32x4 y0 = *(const f32x4*)(y_ws + (size_t)(2 * t) * NH + c);
    f32x4 y1 = *(const f32x4*)(y_ws + (size_t)(2 * t + 1) * NH + c);
    f32x4 o;
#pragma unroll
    for (int j = 0; j < 4; ++j) o[j] = w0 * y0[j] + w1 * y1[j];
    *(f32x4*)(out + (size_t)t * NH + c) = o;
}

// ================= scalar fallback (ws too small) =================
__global__ __launch_bounds__(256) void moe_kernel(
        const float* __restrict__ x,
        const int*   __restrict__ w13q,
        const int*   __restrict__ w2q,
        const float* __restrict__ s13,
        const float* __restrict__ s2,
        const int*   __restrict__ topk_i,
        const float* __restrict__ topk_w,
        float* __restrict__ out) {
    __shared__ float xs[NH];
    __shared__ float xs8n[HP];
    __shared__ float as[NF];
    __shared__ float as8n[FP];
    const int tid = threadIdx.x;
    const int t   = blockIdx.x;
#pragma unroll
    for (int j = 0; j < NH / 256; ++j)
        xs[j * 256 + tid] = x[t * NH + j * 256 + tid];
    __syncthreads();
    if (tid < HP) {
        float s = 0.f;
#pragma unroll
        for (int p = 0; p < 8; ++p) s += xs[tid * 8 + p];
        xs8n[tid] = -8.f * s;
    }
    __syncthreads();
    float acc[NH / 256];
#pragma unroll
    for (int j = 0; j < NH / 256; ++j) acc[j] = 0.f;
    for (int slot = 0; slot < 2; ++slot) {
        const int   e   = topk_i[t * 2 + slot];
        const float wgt = topk_w[t * 2 + slot];
        const int*   wq = w13q + (size_t)e * HP * TWO_F;
        const float* sc = s13  + (size_t)e * H_GROUPS * TWO_F;
        for (int f = tid; f < NF; f += 256) {
            float gacc = 0.f, uacc = 0.f;
            for (int grp = 0; grp < H_GROUPS; ++grp) {
                float gg = 0.f, uu = 0.f;
#pragma unroll
                for (int kp = grp * 16; kp < grp * 16 + 16; ++kp) {
                    const int qg = wq[kp * TWO_F + f];
                    const int qu = wq[kp * TWO_F + f + NF];
#pragma unroll
                    for (int p = 0; p < 8; ++p) {
                        const float xv = xs[kp * 8 + p];
                        gg += (float)((qg >> (4 * p)) & 15) * xv;
                        uu += (float)((qu >> (4 * p)) & 15) * xv;
                    }
                    const float c8 = xs8n[kp];
                    gg += c8; uu += c8;
                }
                gacc += gg * sc[grp * TWO_F + f];
                uacc += uu * sc[grp * TWO_F + f + NF];
            }
            as[f] = (gacc / (1.f + __expf(-gacc))) * uacc;
        }
        __syncthreads();
        for (int fp = tid; fp < FP; fp += 256) {
            float s = 0.f;
#pragma unroll
            for (int p = 0; p < 8; ++p) s += as[fp * 8 + p];
            as8n[fp] = -8.f * s;
        }
        __syncthreads();
        const int*   wq2 = w2q + (size_t)e * FP * NH;
        const float* sc2 = s2  + (size_t)e * F_GROUPS * NH;
#pragma unroll
        for (int j = 0; j < NH / 256; ++j) {
            const int hh = j * 256 + tid;
            float ysum = 0.f;
            for (int grp = 0; grp < F_GROUPS; ++grp) {
                float gg = 0.f;
#pragma unroll
                for (int fp = grp * 16; fp < grp * 16 + 16; ++fp) {
                    const int q = wq2[fp * NH + hh];
#pragma unroll
                    for (int p = 0; p < 8; ++p)
                        gg += (float)((q >> (4 * p)) & 15) * as[fp * 8 + p];
                    gg += as8n[fp];
                }
                ysum += gg * sc2[grp * NH + hh];
            }
            acc[j] += wgt * ysum;
        }
        __syncthreads();
    }
#pragma unroll
    for (int j = 0; j < NH / 256; ++j)
        out[t * NH + j * 256 + tid] = acc[j];
}

extern "C" void kernel_launch(void* const* d_in, const int* in_sizes, int n_in,
                              void* d_out, int out_size, void* d_ws, size_t ws_size,
                              hipStream_t stream) {
    const float* x      = (const float*)d_in[0];
    const float* logits = (const float*)d_in[1];
    const int*   w13q   = (const int*)d_in[2];
    const int*   w2q    = (const int*)d_in[3];
    const float* s13    = (const float*)d_in[4];
    const float* s2     = (const float*)d_in[5];

    char* ws = (char*)d_ws;
    int*   topk_i  = (int*)ws;                       // 4 KB
    float* topk_w  = (float*)(ws + 4096);            // 4 KB
    int*   counts  = (int*)(ws + 8192);              // 32 B
    int*   tok_list= (int*)(ws + 12288);             // 16 KB
    short* x_bf    = (short*)(ws + 32768);                      // 1 MB
    short* h_ws    = (short*)(ws + 32768 + 1048576);            // 11.5 MB
    short* a_ws    = (short*)(ws + 32768 + 1048576 + 11534336); // 5.77 MB
    float* y_ws    = (float*)(ws + 32768 + 1048576 + 11534336 + 5767168); // 4 MB
    const size_t need = 32768ull + 1048576 + 11534336 + 5767168 + 4194304;

    route_kernel<<<2, 256, 0, stream>>>(logits, topk_i, topk_w);
    if (ws_size >= need) {
        cvt_x_kernel<<<(NT * NH) / (256 * 8), 256, 0, stream>>>(x, x_bf);
        bin_kernel<<<1, 512, 0, stream>>>(topk_i, counts, tok_list);
        gemm1_kernel<<<dim3(TWO_F / 128, 4, NE), 256, 0, stream>>>(
            x_bf, w13q, s13, counts, tok_list, h_ws);
        act_kernel<<<2 * NT, 384, 0, stream>>>(h_ws, a_ws);
        gemm2_kernel<<<dim3(NH / 128, NT / 64, NE), 256, 0, stream>>>(
            a_ws, w2q, s2, counts, tok_list, y_ws);
        combine_kernel<<<NT, 256, 0, stream>>>(y_ws, topk_w, (float*)d_out);
    } else {
        moe_kernel<<<NT, 256, 0, stream>>>(x, w13q, w2q, s13, s2,
                                           topk_i, topk_w, (float*)d_out);
    }
}

// Round 3
// 110.705 us; speedup vs baseline: 12.4409x; 1.4564x over previous
//
#include <hip/hip_runtime.h>
#include <math.h>

#define NE 8
#define NT 512
#define NH 1024
#define NF 2816
#define NG 128
#define TWO_F (2*NF)      // 5632
#define HP (NH/8)         // 128 packed rows for w13
#define FP (NF/8)         // 352 packed rows for w2
#define H_GROUPS (NH/NG)  // 8
#define F_GROUPS (NF/NG)  // 22

typedef __attribute__((ext_vector_type(8))) short short8;
typedef __attribute__((ext_vector_type(4))) float f32x4;

__device__ inline short f2bf(float f) {
    unsigned u = __float_as_uint(f);
    u += 0x7FFFu + ((u >> 16) & 1u);   // RNE
    return (short)(u >> 16);
}

// unpack 8 int4 nibbles -> (nib-8)*sc as bf16 (truncation pack via v_perm)
__device__ inline short8 unpack_scale(int q, float sc) {
    float v[8];
#pragma unroll
    for (int j = 0; j < 8; ++j) {
        unsigned u = 0x4B000000u | (((unsigned)q >> (4 * j)) & 15u);
        v[j] = __uint_as_float(u) - 8388616.0f;   // exact (nib - 8)
    }
    union { short8 s; unsigned u[4]; } r;
#pragma unroll
    for (int j = 0; j < 4; ++j) {
        unsigned lo = __float_as_uint(v[2 * j] * sc);
        unsigned hi = __float_as_uint(v[2 * j + 1] * sc);
        r.u[j] = __builtin_amdgcn_perm(hi, lo, 0x07060302u);  // [bf16(lo), bf16(hi)]
    }
    return r.s;
}

// -------- fused routing (softmax->top2->renorm) + stable expert binning ----
__global__ __launch_bounds__(512) void route_bin_kernel(
        const float* __restrict__ logits,
        float* __restrict__ topk_w,
        int* __restrict__ counts,
        int* __restrict__ tok_list) {
    __shared__ int sh_e[2 * NT];
    const int t = threadIdx.x;   // one token per thread, NT==512
    float l[NE];
#pragma unroll
    for (int e = 0; e < NE; ++e) l[e] = logits[t * NE + e];
    int i0 = 0; float v0 = l[0];
#pragma unroll
    for (int e = 1; e < NE; ++e) { if (l[e] > v0) { v0 = l[e]; i0 = e; } }
    int i1 = -1; float v1 = -INFINITY;
#pragma unroll
    for (int e = 0; e < NE; ++e) {
        if (e == i0) continue;
        if (l[e] > v1) { v1 = l[e]; i1 = e; }
    }
    float e1 = expf(v1 - v0);
    float inv = 1.0f / (1.0f + e1);
    topk_w[t * 2 + 0] = inv;
    topk_w[t * 2 + 1] = e1 * inv;
    sh_e[t * 2 + 0] = i0;
    sh_e[t * 2 + 1] = i1;
    __syncthreads();
    // stable binning: wave w owns expert w
    const int w = t >> 6, lane = t & 63;
    int base = 0;
    for (int chunk = 0; chunk < 16; ++chunk) {
        int j = chunk * 64 + lane;
        bool m = (sh_e[j] == w);
        unsigned long long mask = __ballot(m);
        if (m) {
            int pos = base + __popcll(mask & ((1ull << lane) - 1ull));
            tok_list[w * NT + pos] = j;   // j = t*2 + slot
        }
        base += __popcll(mask);
    }
    if (lane == 0) counts[w] = base;
}

// ---------------- x -> bf16 ----------------
__global__ void cvt_x_kernel(const float* __restrict__ x, short* __restrict__ x_bf) {
    int idx = (blockIdx.x * 256 + threadIdx.x) * 8;
    f32x4 f0 = *(const f32x4*)(x + idx);
    f32x4 f1 = *(const f32x4*)(x + idx + 4);
    short8 o;
#pragma unroll
    for (int j = 0; j < 4; ++j) o[j] = f2bf(f0[j]);
#pragma unroll
    for (int j = 0; j < 4; ++j) o[4 + j] = f2bf(f1[j]);
    *(short8*)(x_bf + idx) = o;
}

// ------- GEMM1 + silu fused: a = silu(x@Wg) * (x@Wu), tile 128M x 64Fpair ---
__global__ __launch_bounds__(256) void gemm1_act_kernel(
        const short* __restrict__ x_bf,
        const int*   __restrict__ w13q,
        const float* __restrict__ s13,
        const int*   __restrict__ counts,
        const int*   __restrict__ tok_list,
        short* __restrict__ a_ws) {
    const int e = blockIdx.z;
    const int me = counts[e];
    if (me == 0) return;
    const int mtile = blockIdx.y;
    if (mtile * 128 >= me) return;
    const int ntile = blockIdx.x;          // 0..43 (64 F-pairs each)
    const int tid = threadIdx.x;
    const int w = tid >> 6, l = tid & 63;
    const int lr = l & 15, kg = l >> 4;
    const int mh = w >> 1, fh = w & 1;
    const int rb  = mtile * 128 + mh * 64;
    const int cbF = ntile * 64 + fh * 32;  // g cols at cbF, u cols at cbF+NF
    const int* tl = tok_list + e * NT;

    const short* xA[4];
#pragma unroll
    for (int ms = 0; ms < 4; ++ms) {
        int i = rb + ms * 16 + lr;
        if (i >= me) i = me - 1;
        xA[ms] = x_bf + (size_t)(tl[i] >> 1) * NH;
    }

    f32x4 accg[4][2], accu[4][2];
#pragma unroll
    for (int ms = 0; ms < 4; ++ms)
#pragma unroll
        for (int ns = 0; ns < 2; ++ns) { accg[ms][ns] = (f32x4)0.0f; accu[ms][ns] = (f32x4)0.0f; }

    for (int kb = 0; kb < H_GROUPS; ++kb) {
        float scg[2], scu[2];
#pragma unroll
        for (int ns = 0; ns < 2; ++ns) {
            size_t sb = (size_t)(e * H_GROUPS + kb) * TWO_F + cbF + ns * 16 + lr;
            scg[ns] = s13[sb];
            scu[ns] = s13[sb + NF];
        }
#pragma unroll
        for (int ks = 0; ks < 4; ++ks) {
            const int k0 = kb * 128 + ks * 32;
            short8 a[4];
#pragma unroll
            for (int ms = 0; ms < 4; ++ms)
                a[ms] = *(const short8*)(xA[ms] + k0 + kg * 8);
            const int kp = (k0 >> 3) + kg;
            const int* bq = w13q + ((size_t)e * HP + kp) * TWO_F + cbF + lr;
            int qg[2], qu[2];
#pragma unroll
            for (int ns = 0; ns < 2; ++ns) { qg[ns] = bq[ns * 16]; qu[ns] = bq[NF + ns * 16]; }
#pragma unroll
            for (int ns = 0; ns < 2; ++ns) {
                short8 bg = unpack_scale(qg[ns], scg[ns]);
                short8 bu = unpack_scale(qu[ns], scu[ns]);
#pragma unroll
                for (int ms = 0; ms < 4; ++ms) {
                    accg[ms][ns] = __builtin_amdgcn_mfma_f32_16x16x32_bf16(a[ms], bg, accg[ms][ns], 0, 0, 0);
                    accu[ms][ns] = __builtin_amdgcn_mfma_f32_16x16x32_bf16(a[ms], bu, accu[ms][ns], 0, 0, 0);
                }
            }
        }
    }
    // epilogue: silu(g)*u -> bf16, C row = kg*4 + r, col = lr
#pragma unroll
    for (int ms = 0; ms < 4; ++ms) {
#pragma unroll
        for (int r = 0; r < 4; ++r) {
            const int orow = rb + ms * 16 + kg * 4 + r;
            if (orow < me) {
                const int t2s = tl[orow];
                short* dst = a_ws + (size_t)t2s * NF + cbF + lr;
#pragma unroll
                for (int ns = 0; ns < 2; ++ns) {
                    const float g = accg[ms][ns][r];
                    const float u = accu[ms][ns][r];
                    const float aval = (g / (1.0f + __expf(-g))) * u;
                    dst[ns * 16] = f2bf(aval);
                }
            }
        }
    }
}

// ------- GEMM2: y += wgt * (A_e @ W2_e), wave K-split(4) + LDS reduce -------
// tile 64M x 64N, 4 waves each cover full tile over interleaved K-groups.
__global__ __launch_bounds__(256) void gemm2_kernel(
        const short* __restrict__ a_ws,
        const int*   __restrict__ w2q,
        const float* __restrict__ s2,
        const int*   __restrict__ counts,
        const int*   __restrict__ tok_list,
        const float* __restrict__ topk_w,
        float* __restrict__ out) {
    __shared__ float red[3][64][68];       // waves 1..3 park their accs (pad 68: conflict-free)
    const int e = blockIdx.z;
    const int me = counts[e];
    if (me == 0) return;
    const int mtile = blockIdx.y;
    if (mtile * 64 >= me) return;
    const int ntile = blockIdx.x;          // 0..15
    const int tid = threadIdx.x;
    const int kh = tid >> 6, l = tid & 63;
    const int lr = l & 15, kg = l >> 4;
    const int rb = mtile * 64;
    const int cb = ntile * 64;
    const int* tl = tok_list + e * NT;

    const short* aA[4];
#pragma unroll
    for (int ms = 0; ms < 4; ++ms) {
        int i = rb + ms * 16 + lr;
        if (i >= me) i = me - 1;
        aA[ms] = a_ws + (size_t)tl[i] * NF;
    }

    f32x4 acc[4][4];
#pragma unroll
    for (int ms = 0; ms < 4; ++ms)
#pragma unroll
        for (int ns = 0; ns < 4; ++ns) acc[ms][ns] = (f32x4)0.0f;

    for (int g = kh; g < F_GROUPS; g += 4) {
        float sc[4];
#pragma unroll
        for (int ns = 0; ns < 4; ++ns)
            sc[ns] = s2[(size_t)(e * F_GROUPS + g) * NH + cb + ns * 16 + lr];
#pragma unroll
        for (int ks = 0; ks < 4; ++ks) {
            const int k0 = g * 128 + ks * 32;
            short8 a[4];
#pragma unroll
            for (int ms = 0; ms < 4; ++ms)
                a[ms] = *(const short8*)(aA[ms] + k0 + kg * 8);
            const int kp = (k0 >> 3) + kg;
            const int* bq = w2q + ((size_t)e * FP + kp) * NH + cb + lr;
            int q[4];
#pragma unroll
            for (int ns = 0; ns < 4; ++ns) q[ns] = bq[ns * 16];
#pragma unroll
            for (int ns = 0; ns < 4; ++ns) {
                short8 b = unpack_scale(q[ns], sc[ns]);
#pragma unroll
                for (int ms = 0; ms < 4; ++ms)
                    acc[ms][ns] = __builtin_amdgcn_mfma_f32_16x16x32_bf16(a[ms], b, acc[ms][ns], 0, 0, 0);
            }
        }
    }

    if (kh > 0) {
#pragma unroll
        for (int ms = 0; ms < 4; ++ms)
#pragma unroll
            for (int ns = 0; ns < 4; ++ns)
#pragma unroll
                for (int r = 0; r < 4; ++r)
                    red[kh - 1][ms * 16 + kg * 4 + r][ns * 16 + lr] = acc[ms][ns][r];
    }
    __syncthreads();
    if (kh == 0) {
#pragma unroll
        for (int ms = 0; ms < 4; ++ms) {
#pragma unroll
            for (int r = 0; r < 4; ++r) {
                const int rowLoc = ms * 16 + kg * 4 + r;
                const int orow = rb + rowLoc;
                if (orow < me) {
                    const int t2s = tl[orow];
                    const int t   = t2s >> 1;
                    const float wgt = topk_w[t2s];
#pragma unroll
                    for (int ns = 0; ns < 4; ++ns) {
                        float v = acc[ms][ns][r]
                                + red[0][rowLoc][ns * 16 + lr]
                                + red[1][rowLoc][ns * 16 + lr]
                                + red[2][rowLoc][ns * 16 + lr];
                        // exactly 2 atomic adds per out element (slot0, slot1):
                        // f32 add is commutative -> bit-deterministic
                        atomicAdd(out + (size_t)t * NH + cb + ns * 16 + lr, wgt * v);
                    }
                }
            }
        }
    }
}

extern "C" void kernel_launch(void* const* d_in, const int* in_sizes, int n_in,
                              void* d_out, int out_size, void* d_ws, size_t ws_size,
                              hipStream_t stream) {
    const float* x      = (const float*)d_in[0];
    const float* logits = (const float*)d_in[1];
    const int*   w13q   = (const int*)d_in[2];
    const int*   w2q    = (const int*)d_in[3];
    const float* s13    = (const float*)d_in[4];
    const float* s2     = (const float*)d_in[5];

    char* ws = (char*)d_ws;
    int*   counts   = (int*)ws;                         // 32 B
    float* topk_w   = (float*)(ws + 4096);              // 4 KB
    int*   tok_list = (int*)(ws + 8192);                // 16 KB
    short* x_bf     = (short*)(ws + 32768);             // 1 MB
    short* a_ws     = (short*)(ws + 32768 + 1048576);   // 5.77 MB

    hipMemsetAsync(d_out, 0, (size_t)out_size * sizeof(float), stream);
    route_bin_kernel<<<1, 512, 0, stream>>>(logits, topk_w, counts, tok_list);
    cvt_x_kernel<<<(NT * NH) / (256 * 8), 256, 0, stream>>>(x, x_bf);
    gemm1_act_kernel<<<dim3(NF / 64, 4, NE), 256, 0, stream>>>(
        x_bf, w13q, s13, counts, tok_list, a_ws);
    gemm2_kernel<<<dim3(NH / 64, 8, NE), 256, 0, stream>>>(
        a_ws, w2q, s2, counts, tok_list, topk_w, (float*)d_out);
}